// Round 1
// baseline (6365.253 us; speedup 1.0000x reference)
//
#include <hip/hip_runtime.h>

// LSTMCellModel: only seq row 1023 feeds the output => batch-1 recurrence.
// New structure: 4 dispatches total.
//   k_init  : zero zbuf (h0) + flags
//   k_prep  : A[t][cell][row] = w_ih[row,:]·(255*x[t,1023,:]) + b_ih + b_hh  (t-tiled)
//   k_recur : ONE persistent kernel, 256 WGs, Whh entirely in VGPRs (128 f/thread),
//             256 phases separated by a device-scope flag barrier. c stays in regs.
//   k_fc    : out = Hh @ wfc^T + bfc
// ws layout (floats): A[128][2][4096] | Hh[128][1024] | htmp[1024] | zbuf[1024] | flags[256 ints]

#define IN_DIM 512
#define HDIM   1024
#define G4     4096
#define NSTEP  128
#define ODIM   1000

__device__ __forceinline__ float sigf(float x) { return 1.f / (1.f + __expf(-x)); }

__global__ void k_init(float* __restrict__ zbuf, int* __restrict__ flags) {
    int i = threadIdx.x + blockIdx.x * blockDim.x;
    if (i < HDIM) zbuf[i] = 0.f;
    if (i < 256)  flags[i] = 0;
}

// grid 512 WGs x 256 thr; WG = 16 consecutive rows of the combined 8192-row space.
// x staged 8 steps at a time to amortize global-load latency (was 128 serial loads).
__global__ void k_prep(const float* __restrict__ x,
                       const float* __restrict__ wih1, const float* __restrict__ bih1,
                       const float* __restrict__ bhh1,
                       const float* __restrict__ wih2, const float* __restrict__ bih2,
                       const float* __restrict__ bhh2,
                       float* __restrict__ A) {
    __shared__ __align__(16) float Wsh[16][IN_DIM];   // 32 KB
    __shared__ __align__(16) float xs[8][IN_DIM];     // 16 KB
    const int R0   = blockIdx.x * 16;
    const int cell = R0 >> 12;        // blocks never straddle cells
    const int row0 = R0 & 4095;
    const float* __restrict__ wih = cell ? wih2 : wih1;
    const float* __restrict__ bih = cell ? bih2 : bih1;
    const float* __restrict__ bhh = cell ? bhh2 : bhh1;
    const int tid = threadIdx.x;

    for (int idx = tid; idx < 16 * (IN_DIM / 4); idx += 256) {
        int r = idx >> 7, c4 = idx & 127;
        float4 v = ((const float4*)(wih + (size_t)(row0 + r) * IN_DIM))[c4];
        *(float4*)&Wsh[r][c4 * 4] = v;
    }
    const int row_local = tid >> 4;
    const int lane16    = tid & 15;
    const float bias = bih[row0 + row_local] + bhh[row0 + row_local];

    for (int t0 = 0; t0 < NSTEP; t0 += 8) {
        __syncthreads();  // covers W staging (first iter) and xs reuse
        for (int idx = tid; idx < 8 * (IN_DIM / 4); idx += 256) {
            int tt = idx >> 7, c4 = idx & 127;
            float4 v = ((const float4*)(x + ((size_t)(t0 + tt) * 1024 + 1023) * IN_DIM))[c4];
            v.x *= 255.f; v.y *= 255.f; v.z *= 255.f; v.w *= 255.f;
            *(float4*)&xs[tt][c4 * 4] = v;
        }
        __syncthreads();
#pragma unroll
        for (int tt = 0; tt < 8; ++tt) {
            float p = 0.f;
#pragma unroll
            for (int m = 0; m < 32; ++m)
                p += Wsh[row_local][lane16 + 16 * m] * xs[tt][lane16 + 16 * m];
            p += __shfl_xor(p, 8); p += __shfl_xor(p, 4);
            p += __shfl_xor(p, 2); p += __shfl_xor(p, 1);
            if (lane16 == 0)
                A[((size_t)(t0 + tt) * 2 + cell) * G4 + row0 + row_local] = p + bias;
        }
    }
}

// One LSTM cell phase inside the persistent kernel.
// Thread (row16=tid>>4, lane16=tid&15): gate g=row16>>2, output k=row16&3,
// Whh row R=g*1024+j0+k, slice = elements [lane16*64, +64) held in wreg.
// hs is XOR-swizzled: logical i=(c=i>>6, g=(i>>2)&15, e=i&3) stored at
// phys c*64 + ((g+c)&15)*4 + e  -> b128 reads are ~2-way conflict (free).
__device__ __forceinline__ void lstm_phase(
    const float (&wreg)[64], const float* __restrict__ Ab,
    const float* __restrict__ hin, float* __restrict__ hout,
    int pc, int* __restrict__ flags, float* __restrict__ hs, float* __restrict__ gs,
    float& c_val, int tid, int wg, int j0, int row16, int lane16, int R)
{
    float aval = 0.f;
    if (lane16 == 0) aval = Ab[R];   // issued before the poll; completes during it
    if (pc > 1) {
        const int target = pc - 1;
        while (!__syncthreads_and(
            __hip_atomic_load(&flags[tid], __ATOMIC_ACQUIRE, __HIP_MEMORY_SCOPE_AGENT)
                >= target)) {}
    }
    // broadcast h through LLC (device-scope => immune to stale per-XCD L2)
    float hv[4];
#pragma unroll
    for (int e = 0; e < 4; ++e)
        hv[e] = __hip_atomic_load(const_cast<float*>(&hin[e * 256 + tid]),
                                  __ATOMIC_RELAXED, __HIP_MEMORY_SCOPE_AGENT);
    const int gg = (tid >> 2) & 15, el = tid & 3;
#pragma unroll
    for (int e = 0; e < 4; ++e) {
        int c = (e << 2) + (tid >> 6);
        hs[c * 64 + (((gg + c) & 15) << 2) + el] = hv[e];
    }
    __syncthreads();
    // 64 FMAs/thread, W from VGPRs, h via swizzled b128 LDS reads; 4 acc chains
    float a0 = 0.f, a1 = 0.f, a2 = 0.f, a3 = 0.f;
    const int hbase = lane16 * 64;
#pragma unroll
    for (int m = 0; m < 16; ++m) {
        const float4 h4 = *(const float4*)&hs[hbase + (((m + lane16) & 15) << 2)];
        a0 += wreg[4 * m + 0] * h4.x;
        a1 += wreg[4 * m + 1] * h4.y;
        a2 += wreg[4 * m + 2] * h4.z;
        a3 += wreg[4 * m + 3] * h4.w;
    }
    float acc = (a0 + a1) + (a2 + a3);
    acc += __shfl_xor(acc, 8); acc += __shfl_xor(acc, 4);
    acc += __shfl_xor(acc, 2); acc += __shfl_xor(acc, 1);
    if (lane16 == 0) gs[row16] = acc + aval;
    __syncthreads();
    if (tid < 4) {  // output j0+tid; c lives in these threads' registers
        float iv = gs[tid], fv = gs[4 + tid], gv = gs[8 + tid], ov = gs[12 + tid];
        float cn = sigf(fv) * c_val + sigf(iv) * tanhf(gv);
        c_val = cn;
        __hip_atomic_store(&hout[j0 + tid], sigf(ov) * tanhf(cn),
                           __ATOMIC_RELAXED, __HIP_MEMORY_SCOPE_AGENT);
    }
    __syncthreads();  // drain h stores (compiler emits vmcnt(0) before s_barrier)
    if (tid == 0)
        __hip_atomic_store(&flags[wg], pc, __ATOMIC_RELEASE, __HIP_MEMORY_SCOPE_AGENT);
}

// grid 256 WGs x 256 thr. Capacity >= 2 WGs/CU at this footprint, so all 256 WGs
// are co-resident under any packing -> spin barrier is deadlock-free.
__global__ __launch_bounds__(256, 1) void k_recur(
    const float* __restrict__ whh1, const float* __restrict__ whh2,
    const float* __restrict__ A, const float* __restrict__ zbuf,
    float* __restrict__ htmp, float* __restrict__ Hh, int* __restrict__ flags)
{
    __shared__ __align__(16) float hs[HDIM];
    __shared__ float gs[16];
    const int tid = threadIdx.x;
    const int wg  = blockIdx.x;
    const int j0  = wg << 2;
    const int row16 = tid >> 4, lane16 = tid & 15;
    const int g = row16 >> 2, k = row16 & 3;
    const int R = g * HDIM + j0 + k;

    // pin both cells' Whh slices in VGPRs: 128 floats/thread, one-time ~34 MB read
    float w1[64], w2[64];
    {
        const float4* p1 = (const float4*)(whh1 + (size_t)R * HDIM + lane16 * 64);
        const float4* p2 = (const float4*)(whh2 + (size_t)R * HDIM + lane16 * 64);
#pragma unroll
        for (int m = 0; m < 16; ++m) {
            float4 v = p1[m];
            w1[4 * m + 0] = v.x; w1[4 * m + 1] = v.y;
            w1[4 * m + 2] = v.z; w1[4 * m + 3] = v.w;
        }
#pragma unroll
        for (int m = 0; m < 16; ++m) {
            float4 v = p2[m];
            w2[4 * m + 0] = v.x; w2[4 * m + 1] = v.y;
            w2[4 * m + 2] = v.z; w2[4 * m + 3] = v.w;
        }
    }
    float c_val = 0.f;
#pragma unroll 1
    for (int t = 0; t < NSTEP; ++t) {
        const float* hin1 = (t == 0) ? zbuf : (Hh + (size_t)(t - 1) * HDIM);
        lstm_phase(w1, A + ((size_t)t * 2 + 0) * G4, hin1, htmp,
                   2 * t + 1, flags, hs, gs, c_val, tid, wg, j0, row16, lane16, R);
        lstm_phase(w2, A + ((size_t)t * 2 + 1) * G4, htmp, Hh + (size_t)t * HDIM,
                   2 * t + 2, flags, hs, gs, c_val, tid, wg, j0, row16, lane16, R);
    }
}

// out[t][o] = Hh[t] . wfc[o] + bfc[o]. grid 125 WGs x 256 thr (8 o per WG).
__global__ void k_fc(const float* __restrict__ Hh, const float* __restrict__ wfc,
                     const float* __restrict__ bfc, float* __restrict__ out) {
    __shared__ float Wf[8][HDIM];
    const int tid = threadIdx.x;
    const int o0  = blockIdx.x * 8;
    for (int idx = tid; idx < 8 * (HDIM / 4); idx += 256) {
        int r  = idx >> 8;
        int c4 = idx & 255;
        float4 v = ((const float4*)(wfc + (size_t)(o0 + r) * HDIM))[c4];
        Wf[r][c4 * 4 + 0] = v.x; Wf[r][c4 * 4 + 1] = v.y;
        Wf[r][c4 * 4 + 2] = v.z; Wf[r][c4 * 4 + 3] = v.w;
    }
    __syncthreads();
    const int ol = tid >> 5, lane32 = tid & 31;
    const float bias = bfc[o0 + ol];
    for (int t = 0; t < NSTEP; ++t) {
        const float* __restrict__ hv = Hh + (size_t)t * HDIM;
        float p = 0.f;
#pragma unroll
        for (int m = 0; m < 32; ++m)
            p += hv[lane32 + 32 * m] * Wf[ol][lane32 + 32 * m];
        p += __shfl_xor(p, 16); p += __shfl_xor(p, 8); p += __shfl_xor(p, 4);
        p += __shfl_xor(p, 2);  p += __shfl_xor(p, 1);
        if (lane32 == 0)
            out[t * ODIM + o0 + ol] = p + bias;
    }
}

extern "C" void kernel_launch(void* const* d_in, const int* in_sizes, int n_in,
                              void* d_out, int out_size, void* d_ws, size_t ws_size,
                              hipStream_t stream) {
    const float* x    = (const float*)d_in[0];
    const float* wih1 = (const float*)d_in[1];
    const float* whh1 = (const float*)d_in[2];
    const float* bih1 = (const float*)d_in[3];
    const float* bhh1 = (const float*)d_in[4];
    const float* wih2 = (const float*)d_in[5];
    const float* whh2 = (const float*)d_in[6];
    const float* bih2 = (const float*)d_in[7];
    const float* bhh2 = (const float*)d_in[8];
    const float* wfc  = (const float*)d_in[9];
    const float* bfc  = (const float*)d_in[10];
    float* out = (float*)d_out;

    float* A     = (float*)d_ws;                  // 128*2*4096
    float* Hh    = A + (size_t)NSTEP * 2 * G4;    // 128*1024
    float* htmp  = Hh + (size_t)NSTEP * HDIM;     // 1024
    float* zbuf  = htmp + HDIM;                   // 1024 (h0 == 0)
    int*   flags = (int*)(zbuf + HDIM);           // 256 ints, re-zeroed every launch

    hipLaunchKernelGGL(k_init, dim3(4), dim3(256), 0, stream, zbuf, flags);
    hipLaunchKernelGGL(k_prep, dim3(512), dim3(256), 0, stream,
                       x, wih1, bih1, bhh1, wih2, bih2, bhh2, A);
    hipLaunchKernelGGL(k_recur, dim3(256), dim3(256), 0, stream,
                       whh1, whh2, A, zbuf, htmp, Hh, flags);
    hipLaunchKernelGGL(k_fc, dim3(125), dim3(256), 0, stream, Hh, wfc, bfc, out);
}

// Round 2
// 1876.280 us; speedup vs baseline: 3.3925x; 3.3925x over previous
//
#include <hip/hip_runtime.h>

// LSTMCellModel: only seq row 1023 feeds the output => batch-1 recurrence.
// 4 dispatches: k_init | k_prep | k_recur (persistent, 256 phases) | k_fc.
// ws layout (floats): A[128][2][4096] | Hh[128][1024] | htmp[1024] | zbuf[1024] | flags[256*32 ints]

#define IN_DIM 512
#define HDIM   1024
#define G4     4096
#define NSTEP  128
#define ODIM   1000
#define NWG    256
#define FSTRIDE 32   // ints => 128 B per flag, one cache line each (no line sharing)

__device__ __forceinline__ float sigf(float x) { return 1.f / (1.f + __expf(-x)); }

__global__ void k_init(float* __restrict__ zbuf, int* __restrict__ flags) {
    int i = threadIdx.x + blockIdx.x * blockDim.x;   // 4 WGs x 256 = 1024 threads
    if (i < HDIM) zbuf[i] = 0.f;
    for (int j = i; j < NWG * FSTRIDE; j += 1024) flags[j] = 0;
}

// grid 512 WGs x 256 thr; WG = 16 consecutive rows of the combined 8192-row space.
__global__ void k_prep(const float* __restrict__ x,
                       const float* __restrict__ wih1, const float* __restrict__ bih1,
                       const float* __restrict__ bhh1,
                       const float* __restrict__ wih2, const float* __restrict__ bih2,
                       const float* __restrict__ bhh2,
                       float* __restrict__ A) {
    __shared__ __align__(16) float Wsh[16][IN_DIM];   // 32 KB
    __shared__ __align__(16) float xs[8][IN_DIM];     // 16 KB
    const int R0   = blockIdx.x * 16;
    const int cell = R0 >> 12;
    const int row0 = R0 & 4095;
    const float* __restrict__ wih = cell ? wih2 : wih1;
    const float* __restrict__ bih = cell ? bih2 : bih1;
    const float* __restrict__ bhh = cell ? bhh2 : bhh1;
    const int tid = threadIdx.x;

    for (int idx = tid; idx < 16 * (IN_DIM / 4); idx += 256) {
        int r = idx >> 7, c4 = idx & 127;
        float4 v = ((const float4*)(wih + (size_t)(row0 + r) * IN_DIM))[c4];
        *(float4*)&Wsh[r][c4 * 4] = v;
    }
    const int row_local = tid >> 4;
    const int lane16    = tid & 15;
    const float bias = bih[row0 + row_local] + bhh[row0 + row_local];

    for (int t0 = 0; t0 < NSTEP; t0 += 8) {
        __syncthreads();  // covers W staging (first iter) and xs reuse
        for (int idx = tid; idx < 8 * (IN_DIM / 4); idx += 256) {
            int tt = idx >> 7, c4 = idx & 127;
            float4 v = ((const float4*)(x + ((size_t)(t0 + tt) * 1024 + 1023) * IN_DIM))[c4];
            v.x *= 255.f; v.y *= 255.f; v.z *= 255.f; v.w *= 255.f;
            *(float4*)&xs[tt][c4 * 4] = v;
        }
        __syncthreads();
#pragma unroll
        for (int tt = 0; tt < 8; ++tt) {
            float p = 0.f;
#pragma unroll
            for (int m = 0; m < 32; ++m)
                p += Wsh[row_local][lane16 + 16 * m] * xs[tt][lane16 + 16 * m];
            p += __shfl_xor(p, 8); p += __shfl_xor(p, 4);
            p += __shfl_xor(p, 2); p += __shfl_xor(p, 1);
            if (lane16 == 0)
                A[((size_t)(t0 + tt) * 2 + cell) * G4 + row0 + row_local] = p + bias;
        }
    }
}

// One LSTM cell phase. Wave w owns output j = wg*4 + w; its 4 gate rows
// (g = lane>>4) are reduced in-wave: no LDS round-trip for the gate combine.
// hs XOR-swizzle: logical i=(c=i>>6, g=(i>>2)&15, e=i&3) at phys
// c*64 + ((g+c)&15)*4 + e  -> both write and b128 read are 2-way (free).
__device__ __forceinline__ void lstm_phase(
    const float (&wreg)[64], const float* __restrict__ Ab,
    const float* __restrict__ hin, float* __restrict__ hout,
    int pc, int* __restrict__ flags, float* __restrict__ hs,
    float& c_val, int tid, int wg, int j, int g, int lane16)
{
    float aval = 0.f;
    if (lane16 == 0) aval = Ab[g * HDIM + j];   // in flight during the poll
    if (pc > 1) {
        const int target = pc - 1;
        if (tid < 64) {                 // ONLY wave 0 polls: 64 lanes x 4 flags
            for (;;) {
                int ok = 1;
#pragma unroll
                for (int e = 0; e < 4; ++e) {
                    int f = __hip_atomic_load(&flags[(tid * 4 + e) * FSTRIDE],
                                              __ATOMIC_RELAXED, __HIP_MEMORY_SCOPE_AGENT);
                    ok &= (f >= target);
                }
                if (__all(ok)) break;
            }
        }
        __syncthreads();
    }
    // broadcast h through LLC (device-scope => immune to stale per-XCD L2)
    float hv[4];
#pragma unroll
    for (int e = 0; e < 4; ++e)
        hv[e] = __hip_atomic_load(const_cast<float*>(&hin[e * 256 + tid]),
                                  __ATOMIC_RELAXED, __HIP_MEMORY_SCOPE_AGENT);
    const int gg = (tid >> 2) & 15, el = tid & 3;
#pragma unroll
    for (int e = 0; e < 4; ++e) {
        int c = (e << 2) + (tid >> 6);
        hs[c * 64 + (((gg + c) & 15) << 2) + el] = hv[e];
    }
    __syncthreads();
    // 64 FMAs/thread: W from VGPRs, h via swizzled b128 LDS reads, 4 acc chains
    float a0 = 0.f, a1 = 0.f, a2 = 0.f, a3 = 0.f;
    const int hbase = lane16 * 64;
#pragma unroll
    for (int m = 0; m < 16; ++m) {
        const float4 h4 = *(const float4*)&hs[hbase + (((m + lane16) & 15) << 2)];
        a0 += wreg[4 * m + 0] * h4.x;
        a1 += wreg[4 * m + 1] * h4.y;
        a2 += wreg[4 * m + 2] * h4.z;
        a3 += wreg[4 * m + 3] * h4.w;
    }
    float acc = (a0 + a1) + (a2 + a3);
    acc += __shfl_xor(acc, 8); acc += __shfl_xor(acc, 4);
    acc += __shfl_xor(acc, 2); acc += __shfl_xor(acc, 1);
    acc += aval;                       // only lane16==0 lanes carry aval
    // gates for output j live at lanes 0(i),16(f),32(g),48(o) of this wave
    const float iv = __shfl(acc, 0),  fv = __shfl(acc, 16),
                gv = __shfl(acc, 32), ov = __shfl(acc, 48);
    const float cn = sigf(fv) * c_val + sigf(iv) * tanhf(gv);
    c_val = cn;                        // wave-replicated cell state
    const float hn = sigf(ov) * tanhf(cn);
    if ((tid & 63) == 0)
        __hip_atomic_store(&hout[j], hn, __ATOMIC_RELAXED, __HIP_MEMORY_SCOPE_AGENT);
    __syncthreads();                   // drains every wave's h store (vmcnt0)
    if (tid == 0)
        __hip_atomic_store(&flags[wg * FSTRIDE], pc,
                           __ATOMIC_RELEASE, __HIP_MEMORY_SCOPE_AGENT);
}

// grid 256 WGs x 256 thr, all co-resident (>=2 WGs/CU even at ~200 VGPRs).
__global__ __launch_bounds__(256, 1) void k_recur(
    const float* __restrict__ whh1, const float* __restrict__ whh2,
    const float* __restrict__ A, const float* __restrict__ zbuf,
    float* __restrict__ htmp, float* __restrict__ Hh, int* __restrict__ flags)
{
    __shared__ __align__(16) float hs[HDIM];
    const int tid    = threadIdx.x;
    const int wg     = blockIdx.x;
    const int lane   = tid & 63;
    const int wv     = tid >> 6;        // wave id = output within the WG's 4
    const int g      = lane >> 4;       // gate row group (i,f,g,o)
    const int lane16 = tid & 15;
    const int j      = (wg << 2) + wv;  // h-output owned by this wave
    const int R      = g * HDIM + j;    // Whh row handled by this thread group

    // pin both cells' Whh row slices in VGPRs: 128 floats/thread.
    float w1[64], w2[64];
    {
        const float4* p1 = (const float4*)(whh1 + (size_t)R * HDIM) + lane16 * 16;
        const float4* p2 = (const float4*)(whh2 + (size_t)R * HDIM) + lane16 * 16;
#pragma unroll
        for (int m = 0; m < 16; ++m) {
            float4 v = p1[m];
            w1[4 * m + 0] = v.x; w1[4 * m + 1] = v.y;
            w1[4 * m + 2] = v.z; w1[4 * m + 3] = v.w;
        }
#pragma unroll
        for (int m = 0; m < 16; ++m) {
            float4 v = p2[m];
            w2[4 * m + 0] = v.x; w2[4 * m + 1] = v.y;
            w2[4 * m + 2] = v.z; w2[4 * m + 3] = v.w;
        }
        // opaque touch: blocks rematerialization of the loads (compiler held
        // only 124 VGPRs last round => weights were re-fetched every phase)
#pragma unroll
        for (int m = 0; m < 64; ++m) {
            asm volatile("" : "+v"(w1[m]));
            asm volatile("" : "+v"(w2[m]));
        }
    }
    float c_val = 0.f;                 // single c chain threads cell1 -> cell2
#pragma unroll 1
    for (int t = 0; t < NSTEP; ++t) {
        const float* hin1 = (t == 0) ? zbuf : (Hh + (size_t)(t - 1) * HDIM);
        lstm_phase(w1, A + ((size_t)t * 2 + 0) * G4, hin1, htmp,
                   2 * t + 1, flags, hs, c_val, tid, wg, j, g, lane16);
        lstm_phase(w2, A + ((size_t)t * 2 + 1) * G4, htmp, Hh + (size_t)t * HDIM,
                   2 * t + 2, flags, hs, c_val, tid, wg, j, g, lane16);
    }
}

// out[t][o] = Hh[t] . wfc[o] + bfc[o]. grid 125 WGs x 256 thr (8 o per WG).
__global__ void k_fc(const float* __restrict__ Hh, const float* __restrict__ wfc,
                     const float* __restrict__ bfc, float* __restrict__ out) {
    __shared__ float Wf[8][HDIM];
    const int tid = threadIdx.x;
    const int o0  = blockIdx.x * 8;
    for (int idx = tid; idx < 8 * (HDIM / 4); idx += 256) {
        int r  = idx >> 8;
        int c4 = idx & 255;
        float4 v = ((const float4*)(wfc + (size_t)(o0 + r) * HDIM))[c4];
        Wf[r][c4 * 4 + 0] = v.x; Wf[r][c4 * 4 + 1] = v.y;
        Wf[r][c4 * 4 + 2] = v.z; Wf[r][c4 * 4 + 3] = v.w;
    }
    __syncthreads();
    const int ol = tid >> 5, lane32 = tid & 31;
    const float bias = bfc[o0 + ol];
    for (int t = 0; t < NSTEP; ++t) {
        const float* __restrict__ hv = Hh + (size_t)t * HDIM;
        float p = 0.f;
#pragma unroll
        for (int m = 0; m < 32; ++m)
            p += hv[lane32 + 32 * m] * Wf[ol][lane32 + 32 * m];
        p += __shfl_xor(p, 16); p += __shfl_xor(p, 8); p += __shfl_xor(p, 4);
        p += __shfl_xor(p, 2);  p += __shfl_xor(p, 1);
        if (lane32 == 0)
            out[t * ODIM + o0 + ol] = p + bias;
    }
}

extern "C" void kernel_launch(void* const* d_in, const int* in_sizes, int n_in,
                              void* d_out, int out_size, void* d_ws, size_t ws_size,
                              hipStream_t stream) {
    const float* x    = (const float*)d_in[0];
    const float* wih1 = (const float*)d_in[1];
    const float* whh1 = (const float*)d_in[2];
    const float* bih1 = (const float*)d_in[3];
    const float* bhh1 = (const float*)d_in[4];
    const float* wih2 = (const float*)d_in[5];
    const float* whh2 = (const float*)d_in[6];
    const float* bih2 = (const float*)d_in[7];
    const float* bhh2 = (const float*)d_in[8];
    const float* wfc  = (const float*)d_in[9];
    const float* bfc  = (const float*)d_in[10];
    float* out = (float*)d_out;

    float* A     = (float*)d_ws;                  // 128*2*4096
    float* Hh    = A + (size_t)NSTEP * 2 * G4;    // 128*1024
    float* htmp  = Hh + (size_t)NSTEP * HDIM;     // 1024
    float* zbuf  = htmp + HDIM;                   // 1024 (h0 == 0)
    int*   flags = (int*)(zbuf + HDIM);           // 256*32 ints, zeroed per launch

    hipLaunchKernelGGL(k_init, dim3(4), dim3(256), 0, stream, zbuf, flags);
    hipLaunchKernelGGL(k_prep, dim3(512), dim3(256), 0, stream,
                       x, wih1, bih1, bhh1, wih2, bih2, bhh2, A);
    hipLaunchKernelGGL(k_recur, dim3(256), dim3(256), 0, stream,
                       whh1, whh2, A, zbuf, htmp, Hh, flags);
    hipLaunchKernelGGL(k_fc, dim3(125), dim3(256), 0, stream, Hh, wfc, bfc, out);
}

// Round 3
// 1321.049 us; speedup vs baseline: 4.8183x; 1.4203x over previous
//
#include <hip/hip_runtime.h>

// LSTMCellModel: only seq row 1023 feeds the output => batch-1 recurrence.
// 2 dispatches: k_init | k_fused (persistent, 256 WGs x 512 thr).
//   WGs 0..127  = cell1: pin whh1 rows in VGPRs (64 f/thread), compute A1 on the
//                 fly from x[t] during idle, and the FC output slice from the
//                 h-tile already staged for the matvec.
//   WGs 128..255= cell2: pin whh2 rows, compute A2 on the fly.
//   Flag barrier: each half waits on the OTHER half's 128 line-padded flags,
//   wave0-only poll. c ping-pongs through LLC (c1buf/c2buf).
// ws (floats): zbuf[1024] | htmp[1024] | c1[1024] | c2[1024] | Hh[128*1024] | flags[2*128*32 ints]

#define IN_DIM  512
#define HDIM    1024
#define NSTEP   128
#define ODIM    1000
#define FSTRIDE 32      // ints => 128 B per flag line
#define NWGH    128     // WGs per half
#define NTHR    512

__device__ __forceinline__ float sigf(float x) { return 1.f / (1.f + __expf(-x)); }

__global__ void k_init(float* __restrict__ zbuf, int* __restrict__ flags) {
    int i = threadIdx.x + blockIdx.x * blockDim.x;   // 4 WGs x 1024
    if (i < HDIM) zbuf[i] = 0.f;
    for (int j = i; j < 2 * NWGH * FSTRIDE; j += 4096) flags[j] = 0;
}

// wave0 polls the other half's 128 flags (2 per lane), everyone else waits at the barrier
__device__ __forceinline__ void wait_flags(const int* __restrict__ f, int target, int tid) {
    if (tid < 64) {
        for (;;) {
            int ok = 1;
#pragma unroll
            for (int e = 0; e < 2; ++e) {
                int v = __hip_atomic_load((int*)&f[(tid * 2 + e) * FSTRIDE],
                                          __ATOMIC_RELAXED, __HIP_MEMORY_SCOPE_AGENT);
                ok &= (v >= target);
            }
            if (__all(ok)) break;
        }
    }
    __syncthreads();
}

// broadcast h (1024 f) through LLC into hs with the XOR swizzle:
// logical i=(c=i>>6, g=(i>>2)&15, e=i&3) stored at phys c*64+((g+c)&15)*4+e
__device__ __forceinline__ void load_h(const float* __restrict__ hin,
                                       float* __restrict__ hs, int tid) {
    float hv[2];
#pragma unroll
    for (int e = 0; e < 2; ++e)
        hv[e] = __hip_atomic_load((float*)&hin[e * 512 + tid],
                                  __ATOMIC_RELAXED, __HIP_MEMORY_SCOPE_AGENT);
    const int gg = (tid >> 2) & 15, el = tid & 3;
#pragma unroll
    for (int e = 0; e < 2; ++e) {
        int c = (e << 3) + (tid >> 6);
        hs[c * 64 + (((gg + c) & 15) << 2) + el] = hv[e];
    }
}

__global__ __launch_bounds__(NTHR, 2) void k_fused(
    const float* __restrict__ x,
    const float* __restrict__ wih1, const float* __restrict__ bih1,
    const float* __restrict__ bhh1, const float* __restrict__ whh1,
    const float* __restrict__ wih2, const float* __restrict__ bih2,
    const float* __restrict__ bhh2, const float* __restrict__ whh2,
    const float* __restrict__ wfc, const float* __restrict__ bfc,
    const float* __restrict__ zbuf, float* __restrict__ htmp, float* __restrict__ Hh,
    float* __restrict__ c1buf, float* __restrict__ c2buf,
    int* __restrict__ flags1, int* __restrict__ flags2,
    float* __restrict__ out)
{
    __shared__ __align__(16) float WihL[32 * 516];   // 32 rows, +4 pad vs banks
    __shared__ __align__(16) float WfcL[8 * 1024];
    __shared__ __align__(16) float hs[HDIM];
    __shared__ __align__(16) float xbuf[IN_DIM];

    const int tid  = threadIdx.x;
    const int bid  = blockIdx.x;
    const bool is1 = (bid < NWGH);
    const int wg   = is1 ? bid : bid - NWGH;
    const int lane = tid & 63;
    const int wv   = tid >> 6;          // wave = h-output within WG's 8
    const int g    = lane >> 4;         // gate (i,f,g,o)
    const int lane16 = tid & 15;
    const int j    = wg * 8 + wv;       // owned h index
    const int R    = g * HDIM + j;      // whh/wih row for this 16-lane group

    const float* __restrict__ wih = is1 ? wih1 : wih2;
    const float* __restrict__ whh = is1 ? whh1 : whh2;
    const float* __restrict__ bih = is1 ? bih1 : bih2;
    const float* __restrict__ bhh = is1 ? bhh1 : bhh2;

    // stage this WG's 32 w_ih rows (local row r = wv*4+g)
    for (int idx = tid; idx < 32 * (IN_DIM / 4); idx += NTHR) {
        int r = idx >> 7, c4 = idx & 127;
        int grow = (r & 3) * HDIM + wg * 8 + (r >> 2);
        float4 v = ((const float4*)(wih + (size_t)grow * IN_DIM))[c4];
        *(float4*)&WihL[r * 516 + c4 * 4] = v;
    }
    // cell1 WGs 0..124 own FC outputs o0..o0+7 (125*8 = 1000 exactly)
    const int o0 = wg * 8;
    const bool do_fc = is1 && (wg < 125);
    if (do_fc) {
        for (int idx = tid; idx < 8 * (HDIM / 4); idx += NTHR) {
            int r = idx >> 8, c4 = idx & 255;
            float4 v = ((const float4*)(wfc + (size_t)(o0 + r) * HDIM))[c4];
            *(float4*)&WfcL[r * 1024 + c4 * 4] = v;
        }
    }
    const float bgate = bih[R] + bhh[R];
    const float bfc_r = do_fc ? bfc[o0 + wv] : 0.f;

    // pin whh row slice: 64 floats/thread (elements [lane16*64, +64) of row R)
    float w[64];
    {
        const float4* p = (const float4*)(whh + (size_t)R * HDIM) + lane16 * 16;
#pragma unroll
        for (int m = 0; m < 16; ++m) {
            float4 v = p[m];
            w[4 * m + 0] = v.x; w[4 * m + 1] = v.y;
            w[4 * m + 2] = v.z; w[4 * m + 3] = v.w;
        }
#pragma unroll
        for (int m = 0; m < 64; ++m) asm volatile("" : "+v"(w[m]));
    }

    int* __restrict__ myfl = is1 ? flags1 : flags2;
    const int* __restrict__ otfl = is1 ? flags2 : flags1;

#pragma unroll 1
    for (int t = 0; t < NSTEP; ++t) {
        // ---- pre-work (hidden in the other half's phase) ----
        if (tid < 128) {   // stage x[t] row 1023, scaled by 255
            float4 v = ((const float4*)(x + ((size_t)t * 1024 + 1023) * IN_DIM))[tid];
            v.x *= 255.f; v.y *= 255.f; v.z *= 255.f; v.w *= 255.f;
            *(float4*)&xbuf[tid * 4] = v;
        }
        __syncthreads();
        float av = 0.f;    // per-lane partial of wih[R]·(255 x[t])
        {
            const float* __restrict__ wr = &WihL[(wv * 4 + g) * 516];
#pragma unroll
            for (int m = 0; m < 32; ++m)
                av += wr[lane16 + 16 * m] * xbuf[lane16 + 16 * m];
        }
        // ---- wait for the other half ----
        const float* hin;
        if (is1) {
            if (t > 0) wait_flags(otfl, t, tid);
            hin = (t == 0) ? zbuf : (Hh + (size_t)(t - 1) * HDIM);
        } else {
            wait_flags(otfl, t + 1, tid);
            hin = htmp;
        }
        // ---- stage h + fetch c ----
        load_h(hin, hs, tid);
        float cl = 0.f;
        if (lane == 0 && !(is1 && t == 0)) {
            const float* cb = is1 ? &c2buf[j] : &c1buf[j];
            cl = __hip_atomic_load((float*)cb, __ATOMIC_RELAXED, __HIP_MEMORY_SCOPE_AGENT);
        }
        const float cprev = __shfl(cl, 0);
        __syncthreads();
        // ---- matvec: 64 FMAs from VGPR weights x swizzled LDS h ----
        float a0 = 0.f, a1 = 0.f, a2 = 0.f, a3 = 0.f;
        const int hbase = lane16 * 64;
#pragma unroll
        for (int m = 0; m < 16; ++m) {
            const float4 h4 = *(const float4*)&hs[hbase + (((m + lane16) & 15) << 2)];
            a0 += w[4 * m + 0] * h4.x;
            a1 += w[4 * m + 1] * h4.y;
            a2 += w[4 * m + 2] * h4.z;
            a3 += w[4 * m + 3] * h4.w;
        }
        float acc = (a0 + a1) + (a2 + a3) + av;
        acc += __shfl_xor(acc, 8); acc += __shfl_xor(acc, 4);
        acc += __shfl_xor(acc, 2); acc += __shfl_xor(acc, 1);
        acc += bgate;
        const float iv = __shfl(acc, 0),  fv = __shfl(acc, 16),
                    gv = __shfl(acc, 32), ov = __shfl(acc, 48);
        const float cn = sigf(fv) * cprev + sigf(iv) * tanhf(gv);
        const float hn = sigf(ov) * tanhf(cn);
        if (lane == 0) {
            if (is1) {
                __hip_atomic_store(&c1buf[j], cn, __ATOMIC_RELAXED, __HIP_MEMORY_SCOPE_AGENT);
                __hip_atomic_store(&htmp[j], hn, __ATOMIC_RELAXED, __HIP_MEMORY_SCOPE_AGENT);
            } else {
                __hip_atomic_store(&c2buf[j], cn, __ATOMIC_RELAXED, __HIP_MEMORY_SCOPE_AGENT);
                __hip_atomic_store(&Hh[(size_t)t * HDIM + j], hn,
                                   __ATOMIC_RELAXED, __HIP_MEMORY_SCOPE_AGENT);
            }
        }
        __syncthreads();   // vmcnt(0) drain of all waves' stores before release
        if (tid == 0)
            __hip_atomic_store(&myfl[wg * FSTRIDE], t + 1,
                               __ATOMIC_RELEASE, __HIP_MEMORY_SCOPE_AGENT);
        // ---- FC slice for out[t-1] from hs (= Hh[t-1]); off critical path ----
        if (do_fc && t > 0) {
            const float* __restrict__ wr = &WfcL[wv * 1024];
            const int ggi = (lane >> 2) & 15, ei = lane & 3;
            float p = 0.f;
#pragma unroll
            for (int m = 0; m < 16; ++m)
                p += wr[lane + 64 * m] * hs[m * 64 + (((ggi + m) & 15) << 2) + ei];
            p += __shfl_xor(p, 32); p += __shfl_xor(p, 16); p += __shfl_xor(p, 8);
            p += __shfl_xor(p, 4);  p += __shfl_xor(p, 2);  p += __shfl_xor(p, 1);
            if (lane == 0) out[(size_t)(t - 1) * ODIM + o0 + wv] = p + bfc_r;
        }
    }
    // tail: out[127]
    if (do_fc) {
        wait_flags(flags2, NSTEP, tid);
        load_h(Hh + (size_t)(NSTEP - 1) * HDIM, hs, tid);
        __syncthreads();
        const float* __restrict__ wr = &WfcL[wv * 1024];
        const int ggi = (lane >> 2) & 15, ei = lane & 3;
        float p = 0.f;
#pragma unroll
        for (int m = 0; m < 16; ++m)
            p += wr[lane + 64 * m] * hs[m * 64 + (((ggi + m) & 15) << 2) + ei];
        p += __shfl_xor(p, 32); p += __shfl_xor(p, 16); p += __shfl_xor(p, 8);
        p += __shfl_xor(p, 4);  p += __shfl_xor(p, 2);  p += __shfl_xor(p, 1);
        if (lane == 0) out[(size_t)(NSTEP - 1) * ODIM + o0 + wv] = p + bfc_r;
    }
}

extern "C" void kernel_launch(void* const* d_in, const int* in_sizes, int n_in,
                              void* d_out, int out_size, void* d_ws, size_t ws_size,
                              hipStream_t stream) {
    const float* x    = (const float*)d_in[0];
    const float* wih1 = (const float*)d_in[1];
    const float* whh1 = (const float*)d_in[2];
    const float* bih1 = (const float*)d_in[3];
    const float* bhh1 = (const float*)d_in[4];
    const float* wih2 = (const float*)d_in[5];
    const float* whh2 = (const float*)d_in[6];
    const float* bih2 = (const float*)d_in[7];
    const float* bhh2 = (const float*)d_in[8];
    const float* wfc  = (const float*)d_in[9];
    const float* bfc  = (const float*)d_in[10];
    float* out = (float*)d_out;

    float* zbuf  = (float*)d_ws;                 // 1024
    float* htmp  = zbuf + HDIM;                  // 1024
    float* c1buf = htmp + HDIM;                  // 1024
    float* c2buf = c1buf + HDIM;                 // 1024
    float* Hh    = c2buf + HDIM;                 // 128*1024
    int*   flags = (int*)(Hh + (size_t)NSTEP * HDIM);  // 2*128*32 ints
    int*   flags1 = flags;
    int*   flags2 = flags + NWGH * FSTRIDE;

    hipLaunchKernelGGL(k_init, dim3(4), dim3(1024), 0, stream, zbuf, flags);
    hipLaunchKernelGGL(k_fused, dim3(2 * NWGH), dim3(NTHR), 0, stream,
                       x, wih1, bih1, bhh1, whh1, wih2, bih2, bhh2, whh2,
                       wfc, bfc, zbuf, htmp, Hh, c1buf, c2buf, flags1, flags2, out);
}